// Round 2
// baseline (924.320 us; speedup 1.0000x reference)
//
#include <hip/hip_runtime.h>

typedef __bf16 bf16x8 __attribute__((ext_vector_type(8)));
typedef __bf16 bf16x4 __attribute__((ext_vector_type(4)));
typedef float  f32x4  __attribute__((ext_vector_type(4)));

#define HW   256
#define HW2  65536
#define SK_STRIDE  264   // bf16; 132 dwords == 4 (mod 32) -> conflict-free b128
#define SVT_STRIDE 72    // bf16; 36 dwords == 4 (mod 32) -> conflict-free b128

// 2048 blocks: pair = blk>>1 (b*32+o), h-half = blk&1 (128 rows).
// 512 threads = 8 waves; wave wid owns h rows [h0+16*wid, h0+16*wid+16).
// S^T = K Q'^T  (A-frag = K rows g, B-frag = Q rows h) -> P^T in C-layout,
// which after exp is *natively* the B-operand for O^T = V^T P^T with a
// permuted k-slot order; the permutation is folded into sVT's storage order.
__global__ __launch_bounds__(512, 4) void attn_kernel(
    const float* __restrict__ x1, const float* __restrict__ x2,
    const float* __restrict__ Wq, const float* __restrict__ bq,
    const float* __restrict__ Wk, const float* __restrict__ bk,
    const float* __restrict__ Wv, const float* __restrict__ bv,
    const float* __restrict__ Wa, const float* __restrict__ ba,
    float* __restrict__ out)
{
    __shared__ __align__(16) __bf16 sK [64  * SK_STRIDE];   // 33.8 KB
    __shared__ __align__(16) __bf16 sVT[256 * SVT_STRIDE];  // 36.9 KB

    const int tid  = threadIdx.x;
    const int wid  = tid >> 6;      // 0..7
    const int lane = tid & 63;
    const int quad = lane >> 4;     // 0..3
    const int c    = lane & 15;     // 0..15

    const int blk  = blockIdx.x;
    const int pair = blk >> 1;
    const int ht   = blk & 1;
    const int b    = pair >> 5;
    const int o    = pair & 31;
    const int h0   = ht * 128;

    const float wq0 = Wq[o*3+0], wq1 = Wq[o*3+1], wq2 = Wq[o*3+2], bqv = bq[o];
    const float wk0 = Wk[o*3+0], wk1 = Wk[o*3+1], wk2 = Wk[o*3+2], bkv = bk[o];
    const float wv0 = Wv[o*3+0], wv1 = Wv[o*3+1], wv2 = Wv[o*3+2], bvv = bv[o];
    const float wa0 = Wa[o*3+0], wa1 = Wa[o*3+1], wa2 = Wa[o*3+2], bav = ba[o];
    const float inv = 1.0f / 256.0f;

    const float* x1b = x1 + b * 3 * HW2;
    const float* x2b = x2 + b * 3 * HW2;

    const int hh = h0 + 16*wid + c;      // this lane's h row (S cols / O^T cols)

    // ---------- Q B-frags: qf[kt] holds Q'[h=hh][w = 32*kt + 8*quad + j] ----------
    bf16x8 qf[8];
    {
        const float* r0 = x1b + 0*HW2 + hh*HW;
        const float* r1 = x1b + 1*HW2 + hh*HW;
        const float* r2 = x1b + 2*HW2 + hh*HW;
#pragma unroll
        for (int kt = 0; kt < 8; ++kt) {
            const int wc = 32*kt + 8*quad;
            float4 a0 = *(const float4*)(r0 + wc), a1 = *(const float4*)(r0 + wc + 4);
            float4 b0 = *(const float4*)(r1 + wc), b1 = *(const float4*)(r1 + wc + 4);
            float4 c0 = *(const float4*)(r2 + wc), c1 = *(const float4*)(r2 + wc + 4);
            bf16x8 q;
            q[0] = (__bf16)((wq0*a0.x + wq1*b0.x + wq2*c0.x + bqv) * inv);
            q[1] = (__bf16)((wq0*a0.y + wq1*b0.y + wq2*c0.y + bqv) * inv);
            q[2] = (__bf16)((wq0*a0.z + wq1*b0.z + wq2*c0.z + bqv) * inv);
            q[3] = (__bf16)((wq0*a0.w + wq1*b0.w + wq2*c0.w + bqv) * inv);
            q[4] = (__bf16)((wq0*a1.x + wq1*b1.x + wq2*c1.x + bqv) * inv);
            q[5] = (__bf16)((wq0*a1.y + wq1*b1.y + wq2*c1.y + bqv) * inv);
            q[6] = (__bf16)((wq0*a1.z + wq1*b1.z + wq2*c1.z + bqv) * inv);
            q[7] = (__bf16)((wq0*a1.w + wq1*b1.w + wq2*c1.w + bqv) * inv);
            qf[kt] = q;
        }
    }

    // ---------- S^T phase: per g-chunk stage K, mfma, +A, exp, pack P bf16 ----------
    float lsum = 0.0f;
    bf16x4 pf4[16];   // P^T[g = 16t+4quad+r][h = hh], unnormalized exp, bf16

#pragma unroll
    for (int ci = 0; ci < 4; ++ci) {
        const int g0 = 64 * ci;
        __syncthreads();
        // stage K rows g0..g0+63 row-major (b64 writes, conflict-free)
#pragma unroll
        for (int i = 0; i < 8; ++i) {
            const int s   = i*512 + tid;
            const int row = s >> 6;
            const int c4  = (s & 63) * 4;
            const int g   = g0 + row;
            float4 u0 = *(const float4*)(x2b + 0*HW2 + g*HW + c4);
            float4 u1 = *(const float4*)(x2b + 1*HW2 + g*HW + c4);
            float4 u2 = *(const float4*)(x2b + 2*HW2 + g*HW + c4);
            bf16x4 kv;
            kv[0] = (__bf16)(wk0*u0.x + wk1*u1.x + wk2*u2.x + bkv);
            kv[1] = (__bf16)(wk0*u0.y + wk1*u1.y + wk2*u2.y + bkv);
            kv[2] = (__bf16)(wk0*u0.z + wk1*u1.z + wk2*u2.z + bkv);
            kv[3] = (__bf16)(wk0*u0.w + wk1*u1.w + wk2*u2.w + bkv);
            *(bf16x4*)(&sK[row*SK_STRIDE + c4]) = kv;
        }
        __syncthreads();

#pragma unroll
        for (int tl = 0; tl < 4; ++tl) {
            const int t    = 4*ci + tl;
            const int gcol = 16*t + 4*quad;      // float4 over r (g-contiguous)
            // A-init (fp32 exact): A[h=hh][g = gcol + r]
            float4 A0 = *(const float4*)(x2b + 0*HW2 + hh*HW + gcol);
            float4 A1 = *(const float4*)(x2b + 1*HW2 + hh*HW + gcol);
            float4 A2 = *(const float4*)(x2b + 2*HW2 + hh*HW + gcol);
            f32x4 a;
            a[0] = wa0*A0.x + wa1*A1.x + wa2*A2.x + bav;
            a[1] = wa0*A0.y + wa1*A1.y + wa2*A2.y + bav;
            a[2] = wa0*A0.z + wa1*A1.z + wa2*A2.z + bav;
            a[3] = wa0*A0.w + wa1*A1.w + wa2*A2.w + bav;
#pragma unroll
            for (int kt = 0; kt < 8; ++kt) {
                bf16x8 kf = *(const bf16x8*)(&sK[(16*tl + c)*SK_STRIDE + 32*kt + 8*quad]);
                a = __builtin_amdgcn_mfma_f32_16x16x32_bf16(kf, qf[kt], a, 0, 0, 0);
            }
            // no-max softmax: scores are O(±6), exp safe in fp32
            float e0 = __expf(a[0]), e1 = __expf(a[1]);
            float e2 = __expf(a[2]), e3 = __expf(a[3]);
            lsum += (e0 + e1) + (e2 + e3);
            bf16x4 p;
            p[0] = (__bf16)e0; p[1] = (__bf16)e1;
            p[2] = (__bf16)e2; p[3] = (__bf16)e3;
            pf4[t] = p;
        }
    }

    // row-sum over g: own 64 values done; reduce across quads (same h = hh)
    lsum += __shfl_xor(lsum, 16, 64);
    lsum += __shfl_xor(lsum, 32, 64);
    const float rinv = 1.0f / lsum;

    // ---------- O^T = V^T P^T ----------
    f32x4 oacc[16];
#pragma unroll
    for (int t = 0; t < 16; ++t) oacc[t] = (f32x4){0.f, 0.f, 0.f, 0.f};

#pragma unroll
    for (int ci = 0; ci < 4; ++ci) {
        const int g0 = 64 * ci;
        __syncthreads();
        // stage V^T with k-slot-permuted column order:
        // pos = sub*32 + 8q + 4hi + r  <->  gl = sub*32 + 16hi + 4q + r
        {
            const int w   = tid & 255;
            const int sub = tid >> 8;   // 0..1
#pragma unroll
            for (int q = 0; q < 3+1; ++q) {
                bf16x8 pk;
#pragma unroll
                for (int e = 0; e < 8; ++e) {
                    const int gl = sub*32 + 16*(e>>2) + 4*q + (e&3);
                    const int g  = g0 + gl;
                    float u0 = x2b[0*HW2 + g*HW + w];
                    float u1 = x2b[1*HW2 + g*HW + w];
                    float u2 = x2b[2*HW2 + g*HW + w];
                    pk[e] = (__bf16)(wv0*u0 + wv1*u1 + wv2*u2 + bvv);
                }
                *(bf16x8*)(&sVT[w*SVT_STRIDE + sub*32 + 8*q]) = pk;  // b128, conflict-free
            }
        }
        __syncthreads();

#pragma unroll
        for (int sub2 = 0; sub2 < 2; ++sub2) {
            const int C = 2*ci + sub2;          // K=32 chunk: tiles 2C, 2C+1
            // B-frag: lane's own P values, slot (quad,j) -> g = 32C + [j<4: 4q+j | 16+4q+j-4]
            bf16x8 pb = __builtin_shufflevector(pf4[2*C], pf4[2*C+1], 0,1,2,3,4,5,6,7);
#pragma unroll
            for (int wt = 0; wt < 16; ++wt) {
                bf16x8 vf = *(const bf16x8*)(&sVT[(16*wt + c)*SVT_STRIDE + sub2*32 + 8*quad]);
                oacc[wt] = __builtin_amdgcn_mfma_f32_16x16x32_bf16(vf, pb, oacc[wt], 0, 0, 0);
            }
        }
    }

    // ---------- epilogue: O^T[w = 16wt+4q+r][h = hh] * rinv ----------
    float* outp = out + (size_t)pair * HW2 + (size_t)hh * HW;
#pragma unroll
    for (int wt = 0; wt < 16; ++wt) {
        float4 st;
        st.x = oacc[wt][0] * rinv;
        st.y = oacc[wt][1] * rinv;
        st.z = oacc[wt][2] * rinv;
        st.w = oacc[wt][3] * rinv;
        *(float4*)(outp + 16*wt + 4*quad) = st;
    }
}

extern "C" void kernel_launch(void* const* d_in, const int* in_sizes, int n_in,
                              void* d_out, int out_size, void* d_ws, size_t ws_size,
                              hipStream_t stream) {
    const float* x1 = (const float*)d_in[0];
    const float* x2 = (const float*)d_in[1];
    const float* Wq = (const float*)d_in[2];
    const float* bq = (const float*)d_in[3];
    const float* Wk = (const float*)d_in[4];
    const float* bk = (const float*)d_in[5];
    const float* Wv = (const float*)d_in[6];
    const float* bv = (const float*)d_in[7];
    const float* Wa = (const float*)d_in[8];
    const float* ba = (const float*)d_in[9];
    float* out = (float*)d_out;

    attn_kernel<<<dim3(2048), dim3(512), 0, stream>>>(
        x1, x2, Wq, bq, Wk, bk, Wv, bv, Wa, ba, out);
}